// Round 1
// baseline (2689.177 us; speedup 1.0000x reference)
//
#include <hip/hip_runtime.h>
#include <cstdint>
#include <cstddef>

#define NSTEPS 30

typedef __attribute__((ext_vector_type(4))) float f32x4;
typedef __attribute__((ext_vector_type(8))) short bf16x8;

__device__ __forceinline__ unsigned short f2bf(float f) {
  union { float f; unsigned int u; } v; v.f = f;
  return (unsigned short)((v.u + 0x7FFFu + ((v.u >> 16) & 1u)) >> 16);
}

__device__ __forceinline__ void gload_lds16(const void* g, void* l) {
  __builtin_amdgcn_global_load_lds(
      (const __attribute__((address_space(1))) unsigned int*)g,
      (__attribute__((address_space(3))) unsigned int*)l, 16, 0, 0);
}

// ---------------------------------------------------------------------------
// GEMM: C = A @ B^T, A [M,K] bf16 row-major, B [N,K] bf16 row-major.
// 128x128 tile, BK=32, 4 waves (2x2), 4x4 fragments of mfma 16x16x32 bf16.
// MODE 0: outf[r*N+c] = acc*is + bias[c]                  (x_proj, f32 out)
// MODE 1: outbf[r*N+c] = bf16(tanh(acc*is + xproj + bias)) (recurrent step)
// MODE 2: if c<Nreal: outf[r*Nreal+c] = acc*is + bias[c]   (final output)
// ---------------------------------------------------------------------------
template <int MODE>
__global__ __launch_bounds__(256) void gemm_bt(
    const unsigned short* __restrict__ A, const unsigned short* __restrict__ B,
    int N, int K, int nbn,
    const float* __restrict__ bias, const float* __restrict__ xproj,
    const float* __restrict__ inv_sig,
    float* __restrict__ outf, unsigned short* __restrict__ outbf, int Nreal) {
  __shared__ unsigned short As[128 * 32];
  __shared__ unsigned short Bs[128 * 32];
  const int t = threadIdx.x;
  const int w = t >> 6, l = t & 63;
  const int bm = blockIdx.x / nbn, bn = blockIdx.x % nbn;
  const int row0 = bm << 7, col0 = bn << 7;
  const int wm = w >> 1, wn = w & 1;
  const int lr = l & 15, lkb = (l >> 4) << 3;
  const int srow = l >> 2;          // row within 16-row segment
  const int scol = (l & 3) << 3;    // k element offset 0,8,16,24

  f32x4 acc[4][4];
#pragma unroll
  for (int i = 0; i < 4; ++i)
#pragma unroll
    for (int j = 0; j < 4; ++j) acc[i][j] = (f32x4){0.f, 0.f, 0.f, 0.f};

  for (int k0 = 0; k0 < K; k0 += 32) {
    __syncthreads();
#pragma unroll
    for (int i = 0; i < 2; ++i) {
      const int seg = i * 4 + w;
      const unsigned short* gpA =
          A + (size_t)(row0 + seg * 16 + srow) * K + (k0 + scol);
      gload_lds16(gpA, As + seg * 512);
      const unsigned short* gpB =
          B + (size_t)(col0 + seg * 16 + srow) * K + (k0 + scol);
      gload_lds16(gpB, Bs + seg * 512);
    }
    __syncthreads();
    bf16x8 av[4], bv[4];
#pragma unroll
    for (int f = 0; f < 4; ++f)
      av[f] = *(const bf16x8*)(As + (wm * 64 + f * 16 + lr) * 32 + lkb);
#pragma unroll
    for (int f = 0; f < 4; ++f)
      bv[f] = *(const bf16x8*)(Bs + (wn * 64 + f * 16 + lr) * 32 + lkb);
#pragma unroll
    for (int i = 0; i < 4; ++i)
#pragma unroll
      for (int j = 0; j < 4; ++j)
        acc[i][j] =
            __builtin_amdgcn_mfma_f32_16x16x32_bf16(av[i], bv[j], acc[i][j], 0, 0, 0);
  }

  const float is = inv_sig ? inv_sig[0] : 1.0f;
  const int rbase = row0 + wm * 64 + (l >> 4) * 4;
  const int cbase = col0 + wn * 64 + lr;
#pragma unroll
  for (int i = 0; i < 4; ++i) {
#pragma unroll
    for (int j = 0; j < 4; ++j) {
      const int c = cbase + j * 16;
#pragma unroll
      for (int q = 0; q < 4; ++q) {
        const int r = rbase + i * 16 + q;
        const float v = acc[i][j][q] * is;
        if (MODE == 0) {
          outf[(size_t)r * N + c] = v + bias[c];
        } else if (MODE == 1) {
          const float z = tanhf(v + xproj[(size_t)r * N + c] + bias[c]);
          outbf[(size_t)r * N + c] = f2bf(z);
        } else {
          if (c < Nreal) outf[(size_t)r * Nreal + c] = v + bias[c];
        }
      }
    }
  }
}

// ---------------------------------------------------------------------------
// Tiled fp32 transpose with row padding: out[C][Rpad] = in[Rreal][C]^T (pad 0)
// ---------------------------------------------------------------------------
__global__ __launch_bounds__(256) void transpose_pad(const float* __restrict__ in,
                                                     float* __restrict__ out,
                                                     int Rpad, int C, int Rreal) {
  __shared__ float tile[32][33];
  const int c0 = blockIdx.x * 32, r0 = blockIdx.y * 32;
  const int tx = threadIdx.x & 31, ty = threadIdx.x >> 5;
  for (int i = ty; i < 32; i += 8) {
    const int r = r0 + i;
    tile[i][tx] = (r < Rreal) ? in[(size_t)r * C + (c0 + tx)] : 0.f;
  }
  __syncthreads();
  for (int i = ty; i < 32; i += 8) {
    out[(size_t)(c0 + i) * Rpad + (r0 + tx)] = tile[tx][i];
  }
}

// ---------------------------------------------------------------------------
// Batched row-parallel fp32 matvec: y[r] = (mulv?mulv[r]:1) * (row_r(M) . x)
// 4 waves/block = 4 rows/block; 3 matrices per launch.
// ---------------------------------------------------------------------------
struct MatDesc {
  const float* M;
  const float* x;
  float* y;
  const float* mulv;
  int rows, ld, dot, rreal;
};

__global__ __launch_bounds__(256) void matvec3(MatDesc d0, MatDesc d1, MatDesc d2,
                                               int n0, int n1) {
  int b = blockIdx.x;
  MatDesc d;
  if (b < n0) d = d0;
  else if (b < n0 + n1) { d = d1; b -= n0; }
  else { d = d2; b -= n0 + n1; }
  const int w = threadIdx.x >> 6, l = threadIdx.x & 63;
  const int r = b * 4 + w;
  if (r >= d.rows) return;
  float s = 0.f;
  if (r < d.rreal) {
    const float* Mr = d.M + (size_t)r * d.ld;
#pragma unroll 8
    for (int j = l * 4; j < d.dot; j += 256) {
      const float4 mv = *(const float4*)(Mr + j);
      const float4 xv = *(const float4*)(d.x + j);
      s += mv.x * xv.x + mv.y * xv.y + mv.z * xv.z + mv.w * xv.w;
    }
  }
#pragma unroll
  for (int off = 32; off; off >>= 1) s += __shfl_down(s, off, 64);
  if (l == 0) d.y[r] = (d.mulv ? d.mulv[r] : 1.f) * s;
}

__global__ void init_p(float* p) {
  const int i = blockIdx.x * 256 + threadIdx.x;
  if (i < 5120) p[i] = (i < 5096) ? 1.f : 0.f;  // ones; out-matrix padded rows 0
}

// Single-block deterministic reductions -> inv_sigma[3]
__global__ __launch_bounds__(256) void finalize_sigma(const float* __restrict__ p,
                                                      const float* __restrict__ t,
                                                      const float* __restrict__ cb,
                                                      float* __restrict__ scal) {
  __shared__ float red[256];
  __shared__ float sres[9];
  const int segs[9][2] = {{0, 2048},    {2048, 2048}, {4096, 1024},   // p (squares)
                          {0, 1024},    {1024, 2048}, {3072, 2048},   // t (squares)
                          {0, 2048},    {2048, 2048}, {4096, 1024}};  // cb (plain)
  const float* bases[3] = {p, t, cb};
  for (int s = 0; s < 9; ++s) {
    const float* src = bases[s / 3] + segs[s][0];
    const int len = segs[s][1];
    float acc = 0.f;
    for (int i = threadIdx.x; i < len; i += 256) {
      const float v = src[i];
      acc += (s < 6) ? v * v : v;
    }
    red[threadIdx.x] = acc;
    __syncthreads();
    for (int st = 128; st; st >>= 1) {
      if (threadIdx.x < st) red[threadIdx.x] += red[threadIdx.x + st];
      __syncthreads();
    }
    if (threadIdx.x == 0) sres[s] = red[0];
    __syncthreads();
  }
  if (threadIdx.x == 0) {
    const float eps = 1e-12f;
    for (int m = 0; m < 3; ++m) {
      const float np = sqrtf(sres[m]);
      const float nt = sqrtf(sres[3 + m]);
      const float sig = sres[6 + m] / ((np + eps) * (nt + eps));
      scal[m] = 1.0f / sig;
    }
  }
}

// fp32 -> bf16 with trailing-row zero pad (realTotal..total-1 = 0)
__global__ __launch_bounds__(256) void f32_to_bf16_pad(const float* __restrict__ src,
                                                       unsigned short* __restrict__ dst,
                                                       long realTotal, long total) {
  const long idx = ((long)blockIdx.x * 256 + threadIdx.x) * 4;
  if (idx >= total) return;
  ushort4 o;
  if (idx < realTotal) {
    const float4 v = *(const float4*)(src + idx);
    o.x = f2bf(v.x); o.y = f2bf(v.y); o.z = f2bf(v.z); o.w = f2bf(v.w);
  } else {
    o.x = o.y = o.z = o.w = 0;
  }
  *(ushort4*)(dst + idx) = o;
}

// h1 = tanh(xproj + b_rec)   (first recurrent step: h0 = 0)
__global__ __launch_bounds__(256) void h1_kernel(const float* __restrict__ xproj,
                                                 const float* __restrict__ brec,
                                                 unsigned short* __restrict__ h,
                                                 long total, int N) {
  const long idx = ((long)blockIdx.x * 256 + threadIdx.x) * 4;
  if (idx >= total) return;
  const float4 v = *(const float4*)(xproj + idx);
  const int c = (int)(idx % N);
  const float4 bb = *(const float4*)(brec + c);
  ushort4 o;
  o.x = f2bf(tanhf(v.x + bb.x));
  o.y = f2bf(tanhf(v.y + bb.y));
  o.z = f2bf(tanhf(v.z + bb.z));
  o.w = f2bf(tanhf(v.w + bb.w));
  *(ushort4*)(h + idx) = o;
}

// ---------------------------------------------------------------------------
extern "C" void kernel_launch(void* const* d_in, const int* in_sizes, int n_in,
                              void* d_out, int out_size, void* d_ws, size_t ws_size,
                              hipStream_t stream) {
  const float* x     = (const float*)d_in[0];
  const float* W_in  = (const float*)d_in[1];
  const float* b_in  = (const float*)d_in[2];
  const float* W_rec = (const float*)d_in[3];
  const float* b_rec = (const float*)d_in[4];
  const float* W_out = (const float*)d_in[5];
  const float* b_out = (const float*)d_in[6];
  (void)in_sizes; (void)n_in; (void)out_size; (void)ws_size;

  const int B = 4096, DI = 1024, H = 2048, DO = 1000, DOP = 1024;

  char* ws = (char*)d_ws;
  float* WT_in  = (float*)(ws);                        // [1024][2048]  8MB
  float* WT_rec = (float*)(ws + (size_t)(8u << 20));   // [2048][2048] 16MB
  float* WT_out = (float*)(ws + (size_t)(24u << 20));  // [2048][1024]  8MB
  float* xproj  = (float*)(ws);                        // [4096][2048] 32MB (aliases WT_*)
  unsigned short* Win_bf  = (unsigned short*)(ws + (size_t)(32u << 20));  // 4MB
  unsigned short* Wrec_bf = (unsigned short*)(ws + (size_t)(36u << 20));  // 8MB
  unsigned short* Wout_bf = (unsigned short*)(ws + (size_t)(44u << 20));  // 4MB [1024][2048]
  unsigned short* x_bf    = (unsigned short*)(ws + (size_t)(48u << 20));  // 8MB
  unsigned short* h_a     = (unsigned short*)(ws + (size_t)(56u << 20));  // 16MB
  unsigned short* h_b     = (unsigned short*)(ws + (size_t)(72u << 20));  // 16MB
  float* pvec = (float*)(ws + (size_t)(88u << 20));  // 5120 f
  float* tvec = pvec + 5120;                          // 5120 f
  float* cbuf = tvec + 5120;                          // 5120 f
  float* scal = cbuf + 5120;                          // inv_sigma[3]

  float* p_in = pvec, *p_rec = pvec + 2048, *p_out = pvec + 4096;
  float* t_in = tvec, *t_rec = tvec + 1024, *t_out = tvec + 3072;

  // 1. Transposes (fp32), with W_out padded 1000->1024
  transpose_pad<<<dim3(DI / 32, H / 32), 256, 0, stream>>>(W_in, WT_in, H, DI, H);
  transpose_pad<<<dim3(H / 32, H / 32), 256, 0, stream>>>(W_rec, WT_rec, H, H, H);
  transpose_pad<<<dim3(H / 32, DOP / 32), 256, 0, stream>>>(W_out, WT_out, DOP, H, DO);

  // 2. Power iteration (unnormalized; scale-invariant)
  init_p<<<20, 256, 0, stream>>>(pvec);
  MatDesc f1a = {WT_in, p_in, t_in, nullptr, 1024, 2048, 2048, 1024};
  MatDesc f1b = {WT_rec, p_rec, t_rec, nullptr, 2048, 2048, 2048, 2048};
  MatDesc f1c = {WT_out, p_out, t_out, nullptr, 2048, 1024, 1024, 2048};
  MatDesc f2a = {W_in, t_in, p_in, nullptr, 2048, 1024, 1024, 2048};
  MatDesc f2b = {W_rec, t_rec, p_rec, nullptr, 2048, 2048, 2048, 2048};
  MatDesc f2c = {W_out, t_out, p_out, nullptr, 1024, 2048, 2048, 1000};
  for (int it = 0; it < NSTEPS; ++it) {
    matvec3<<<1280, 256, 0, stream>>>(f1a, f1b, f1c, 256, 512);
    matvec3<<<1280, 256, 0, stream>>>(f2a, f2b, f2c, 512, 512);
  }
  matvec3<<<1280, 256, 0, stream>>>(f1a, f1b, f1c, 256, 512);  // t = W^T u (v raw)

  // 3. sigma contributions c_i = p_i * (row_i(W) . t)
  MatDesc sa = {W_in, t_in, cbuf, p_in, 2048, 1024, 1024, 2048};
  MatDesc sb = {W_rec, t_rec, cbuf + 2048, p_rec, 2048, 2048, 2048, 2048};
  MatDesc sc = {W_out, t_out, cbuf + 4096, p_out, 1024, 2048, 2048, 1000};
  matvec3<<<1280, 256, 0, stream>>>(sa, sb, sc, 512, 512);
  finalize_sigma<<<1, 256, 0, stream>>>(pvec, tvec, cbuf, scal);

  // 4. Convert weights & x to bf16 (unscaled; 1/sigma applied in GEMM epilogue)
  f32_to_bf16_pad<<<2048, 256, 0, stream>>>(W_in, Win_bf, (long)H * DI, (long)H * DI);
  f32_to_bf16_pad<<<4096, 256, 0, stream>>>(W_rec, Wrec_bf, (long)H * H, (long)H * H);
  f32_to_bf16_pad<<<2048, 256, 0, stream>>>(W_out, Wout_bf, (long)DO * H, (long)DOP * H);
  f32_to_bf16_pad<<<4096, 256, 0, stream>>>(x, x_bf, (long)B * DI, (long)B * DI);

  // 5. x_proj = (x @ W_in^T) * is0 + b_in
  gemm_bt<0><<<(B / 128) * (H / 128), 256, 0, stream>>>(
      x_bf, Win_bf, H, DI, H / 128, b_in, nullptr, scal + 0, xproj, nullptr, H);

  // 6. Recurrence: h1 = tanh(xproj + b_rec); then 29 GEMM steps ping-pong
  h1_kernel<<<(int)(((long)B * H / 4 + 255) / 256), 256, 0, stream>>>(
      xproj, b_rec, h_a, (long)B * H, H);
  const unsigned short* hin = h_a;
  unsigned short* hout = h_b;
  for (int s = 2; s <= NSTEPS; ++s) {
    gemm_bt<1><<<(B / 128) * (H / 128), 256, 0, stream>>>(
        hin, Wrec_bf, H, H, H / 128, b_rec, xproj, scal + 1, nullptr, hout, H);
    const unsigned short* tmp = hin;
    hin = hout;
    hout = (unsigned short*)tmp;
  }

  // 7. out = (h @ W_out^T) * is2 + b_out   (N padded to 1024, stores guarded)
  gemm_bt<2><<<(B / 128) * (DOP / 128), 256, 0, stream>>>(
      hin, Wout_bf, DOP, H, DOP / 128, b_out, nullptr, scal + 2,
      (float*)d_out, nullptr, DO);
}

// Round 3
// 1919.347 us; speedup vs baseline: 1.4011x; 1.4011x over previous
//
#include <hip/hip_runtime.h>
#include <cstdint>
#include <cstddef>

#define NSTEPS 30

typedef __attribute__((ext_vector_type(4))) float f32x4;
typedef __attribute__((ext_vector_type(8))) short bf16x8;

__device__ __forceinline__ unsigned short f2bf(float f) {
  union { float f; unsigned int u; } v; v.f = f;
  return (unsigned short)((v.u + 0x7FFFu + ((v.u >> 16) & 1u)) >> 16);
}
__device__ __forceinline__ float bf2f(unsigned short u) {
  union { unsigned int u; float f; } v; v.u = ((unsigned int)u) << 16;
  return v.f;
}

__device__ __forceinline__ void gload_lds16(const void* g, void* l) {
  __builtin_amdgcn_global_load_lds(
      (const __attribute__((address_space(1))) unsigned int*)g,
      (__attribute__((address_space(3))) unsigned int*)l, 16, 0, 0);
}

// ---------------------------------------------------------------------------
// 256x128-tile GEMM, BK=64, safe 2-phase pipeline: C = A @ B^T.
// A [M,K] bf16 row-major, B [N,K] bf16 row-major. 8 waves (4M x 2N),
// per-wave 64x64 output = 4x4 frags of mfma 16x16x32 bf16.
// LDS 96 KiB: A dbuf [256][64] + B dbuf [128][64], XOR-swizzled
// (byte ^= (row&7)<<4 within the 128B row; applied as inverse-swizzled
// GLOBAL source + linear global_load_lds dest + swizzled ds_read — rule 21).
// Schedule per K-tile: STAGE(t+1 -> buf^1); compute(buf); __syncthreads().
// Single barrier per tile drains vmcnt/lgkmcnt => no WAR/RAW races.
// MODE 0: outf[r*N+c] = acc*is + bias[c] + bias2[c]          (xproj, f32)
// MODE 1: outbf[r*N+c] = bf16(tanh(acc*is + xpf[r*N+c]))     (recurrent)
// MODE 2: if c<Nreal: outf[r*Nreal+c] = acc*is + bias[c]     (final out)
// ---------------------------------------------------------------------------
template <int MODE>
__global__ __launch_bounds__(512, 2) void gemm2ph(
    const unsigned short* __restrict__ A, const unsigned short* __restrict__ Bm,
    int N, int K, int nbn, const float* __restrict__ bias,
    const float* __restrict__ bias2, const float* __restrict__ xpf,
    const float* __restrict__ inv_sig, float* __restrict__ outf,
    unsigned short* __restrict__ outbf, int Nreal) {
  __shared__ short lds[49152];  // 96 KiB
  const int t = threadIdx.x, w = t >> 6, l = t & 63;
  const int wm = w >> 1, wn = w & 1;
  const int bm = blockIdx.x / nbn, bn = blockIdx.x % nbn;
  const int row0 = bm << 8, col0 = bn << 7;
  const int NKT = K >> 6;

  f32x4 acc[4][4];
#pragma unroll
  for (int i = 0; i < 4; ++i)
#pragma unroll
    for (int j = 0; j < 4; ++j) acc[i][j] = (f32x4){0.f, 0.f, 0.f, 0.f};

  // Stage K-tile `tile` into buffer `buf`. 6 gload_lds16 per thread:
  // A: 4 x (64 rows), B: 2 x (64 rows). Source k-offset pre-swizzled by
  // ((row&7)<<4) bytes; dest strictly linear (row*128B + (l&7)*16B).
  // row&7 == (l>>3) here, so swizzle = ((l&7) ^ (l>>3)) << 4 bytes.
#define STAGE(tile, buf)                                                      \
  do {                                                                        \
    const int kt_ = (tile) << 6;                                              \
    const int kb_ = (((l & 7) ^ (l >> 3)) << 4) >> 1; /* shorts */            \
    const int rl_ = w * 8 + (l >> 3);                                         \
    _Pragma("unroll") for (int j_ = 0; j_ < 4; ++j_) {                        \
      gload_lds16(A + (size_t)(row0 + j_ * 64 + rl_) * K + kt_ + kb_,         \
                  lds + (buf) * 16384 + j_ * 4096 + w * 512);                 \
    }                                                                         \
    _Pragma("unroll") for (int j_ = 0; j_ < 2; ++j_) {                        \
      gload_lds16(Bm + (size_t)(col0 + j_ * 64 + rl_) * K + kt_ + kb_,        \
                  lds + 32768 + (buf) * 8192 + j_ * 4096 + w * 512);          \
    }                                                                         \
  } while (0)

  STAGE(0, 0);
  __syncthreads();

  const int ar = l & 15;
  const int swzk = (l & 7) << 4;            // bytes
  const int klo = (l >> 4) << 4;            // bytes
  const int kb0 = ((klo ^ swzk) >> 1);      // shorts, k-slice 0
  const int kb1 = (((klo + 64) ^ swzk) >> 1);  // shorts, k-slice 1

  for (int kt = 0; kt < NKT; ++kt) {
    const int cur = kt & 1;
    if (kt + 1 < NKT) STAGE(kt + 1, cur ^ 1);

    bf16x8 av[4][2], bv[4][2];
    const int abase = cur * 16384 + (wm * 64 + ar) * 64;
    const int bbase = 32768 + cur * 8192 + (wn * 64 + ar) * 64;
#pragma unroll
    for (int fm = 0; fm < 4; ++fm) {
      av[fm][0] = *(const bf16x8*)(lds + abase + fm * 1024 + kb0);
      av[fm][1] = *(const bf16x8*)(lds + abase + fm * 1024 + kb1);
    }
#pragma unroll
    for (int fn = 0; fn < 4; ++fn) {
      bv[fn][0] = *(const bf16x8*)(lds + bbase + fn * 1024 + kb0);
      bv[fn][1] = *(const bf16x8*)(lds + bbase + fn * 1024 + kb1);
    }
#pragma unroll
    for (int s = 0; s < 2; ++s)
#pragma unroll
      for (int fm = 0; fm < 4; ++fm)
#pragma unroll
        for (int fn = 0; fn < 4; ++fn)
          acc[fm][fn] = __builtin_amdgcn_mfma_f32_16x16x32_bf16(
              av[fm][s], bv[fn][s], acc[fm][fn], 0, 0, 0);
    __syncthreads();  // drains vmcnt(0)+lgkmcnt(0): tile kt+1 landed, reads done
  }
#undef STAGE

  const float is = inv_sig[0];
#pragma unroll
  for (int fm = 0; fm < 4; ++fm) {
#pragma unroll
    for (int fn = 0; fn < 4; ++fn) {
      const int c = col0 + wn * 64 + fn * 16 + ar;
#pragma unroll
      for (int q = 0; q < 4; ++q) {
        const int r = row0 + wm * 64 + fm * 16 + (l >> 4) * 4 + q;
        const float v = acc[fm][fn][q] * is;
        if (MODE == 0) {
          outf[(size_t)r * N + c] = v + bias[c] + bias2[c];
        } else if (MODE == 1) {
          outbf[(size_t)r * N + c] = f2bf(tanhf(v + xpf[(size_t)r * N + c]));
        } else {
          if (c < Nreal) outf[(size_t)r * Nreal + c] = v + bias[c];
        }
      }
    }
  }
}

// ---------------------------------------------------------------------------
// Tiled transpose f32 -> bf16 with row padding: out[C][Rpad] = bf16(in^T)
// ---------------------------------------------------------------------------
__global__ __launch_bounds__(256) void transpose_pad_b(
    const float* __restrict__ in, unsigned short* __restrict__ out, int Rpad,
    int C, int Rreal) {
  __shared__ float tile[32][33];
  const int c0 = blockIdx.x * 32, r0 = blockIdx.y * 32;
  const int tx = threadIdx.x & 31, ty = threadIdx.x >> 5;
  for (int i = ty; i < 32; i += 8) {
    const int r = r0 + i;
    tile[i][tx] = (r < Rreal) ? in[(size_t)r * C + (c0 + tx)] : 0.f;
  }
  __syncthreads();
  for (int i = ty; i < 32; i += 8) {
    out[(size_t)(c0 + i) * Rpad + (r0 + tx)] = f2bf(tile[tx][i]);
  }
}

// fp32 matvec (sigma pass, exact weights): y[r] = mulv[r] * (row_r(M) . x)
struct MatDesc {
  const float* M;
  const float* x;
  float* y;
  const float* mulv;
  int rows, ld, dot, rreal;
};

__global__ __launch_bounds__(256) void matvec3(MatDesc d0, MatDesc d1,
                                               MatDesc d2, int n0, int n1) {
  int b = blockIdx.x;
  MatDesc d;
  if (b < n0) d = d0;
  else if (b < n0 + n1) { d = d1; b -= n0; }
  else { d = d2; b -= n0 + n1; }
  const int w = threadIdx.x >> 6, l = threadIdx.x & 63;
  const int r = b * 4 + w;
  if (r >= d.rows) return;
  float s = 0.f;
  if (r < d.rreal) {
    const float* Mr = d.M + (size_t)r * d.ld;
#pragma unroll 8
    for (int j = l * 4; j < d.dot; j += 256) {
      const float4 mv = *(const float4*)(Mr + j);
      const float4 xv = *(const float4*)(d.x + j);
      s += mv.x * xv.x + mv.y * xv.y + mv.z * xv.z + mv.w * xv.w;
    }
  }
#pragma unroll
  for (int off = 32; off; off >>= 1) s += __shfl_down(s, off, 64);
  if (l == 0) d.y[r] = (d.mulv ? d.mulv[r] : 1.f) * s;
}

// bf16 matvec (power-iteration passes): y[r] = row_r(M) . x
struct MatDescB {
  const unsigned short* M;
  const float* x;
  float* y;
  int rows, ld, dot;
};

__global__ __launch_bounds__(256) void matvec3b(MatDescB d0, MatDescB d1,
                                                MatDescB d2, int n0, int n1) {
  int b = blockIdx.x;
  MatDescB d;
  if (b < n0) d = d0;
  else if (b < n0 + n1) { d = d1; b -= n0; }
  else { d = d2; b -= n0 + n1; }
  const int w = threadIdx.x >> 6, l = threadIdx.x & 63;
  const int r = b * 4 + w;
  if (r >= d.rows) return;
  const unsigned short* Mr = d.M + (size_t)r * d.ld;
  float s = 0.f;
#pragma unroll 4
  for (int j = l * 8; j < d.dot; j += 512) {
    const bf16x8 mv = *(const bf16x8*)(Mr + j);
    const float4 xa = *(const float4*)(d.x + j);
    const float4 xb = *(const float4*)(d.x + j + 4);
    s += bf2f((unsigned short)mv[0]) * xa.x + bf2f((unsigned short)mv[1]) * xa.y +
         bf2f((unsigned short)mv[2]) * xa.z + bf2f((unsigned short)mv[3]) * xa.w +
         bf2f((unsigned short)mv[4]) * xb.x + bf2f((unsigned short)mv[5]) * xb.y +
         bf2f((unsigned short)mv[6]) * xb.z + bf2f((unsigned short)mv[7]) * xb.w;
  }
#pragma unroll
  for (int off = 32; off; off >>= 1) s += __shfl_down(s, off, 64);
  if (l == 0) d.y[r] = s;
}

__global__ void init_p(float* p) {
  const int i = blockIdx.x * 256 + threadIdx.x;
  if (i < 5120) p[i] = (i < 5096) ? 1.f : 0.f;  // p_out rows 1000..1023 = 0
}

// Single-block deterministic reductions -> inv_sigma[3]
__global__ __launch_bounds__(256) void finalize_sigma(
    const float* __restrict__ p, const float* __restrict__ t,
    const float* __restrict__ cb, float* __restrict__ scal) {
  __shared__ float red[256];
  __shared__ float sres[9];
  const int segs[9][2] = {{0, 2048},    {2048, 2048}, {4096, 1024},
                          {0, 1024},    {1024, 2048}, {3072, 2048},
                          {0, 2048},    {2048, 2048}, {4096, 1024}};
  const float* bases[3] = {p, t, cb};
  for (int s = 0; s < 9; ++s) {
    const float* src = bases[s / 3] + segs[s][0];
    const int len = segs[s][1];
    float acc = 0.f;
    for (int i = threadIdx.x; i < len; i += 256) {
      const float v = src[i];
      acc += (s < 6) ? v * v : v;
    }
    red[threadIdx.x] = acc;
    __syncthreads();
    for (int st = 128; st; st >>= 1) {
      if (threadIdx.x < st) red[threadIdx.x] += red[threadIdx.x + st];
      __syncthreads();
    }
    if (threadIdx.x == 0) sres[s] = red[0];
    __syncthreads();
  }
  if (threadIdx.x == 0) {
    const float eps = 1e-12f;
    for (int m = 0; m < 3; ++m) {
      const float np = sqrtf(sres[m]);
      const float nt = sqrtf(sres[3 + m]);
      const float sig = sres[6 + m] / ((np + eps) * (nt + eps));
      scal[m] = 1.0f / sig;
    }
  }
}

// fp32 -> bf16 with trailing zero pad
__global__ __launch_bounds__(256) void f32_to_bf16_pad(
    const float* __restrict__ src, unsigned short* __restrict__ dst,
    long realTotal, long total) {
  const long idx = ((long)blockIdx.x * 256 + threadIdx.x) * 4;
  if (idx >= total) return;
  ushort4 o;
  if (idx < realTotal) {
    const float4 v = *(const float4*)(src + idx);
    o.x = f2bf(v.x); o.y = f2bf(v.y); o.z = f2bf(v.z); o.w = f2bf(v.w);
  } else {
    o.x = o.y = o.z = o.w = 0;
  }
  *(ushort4*)(dst + idx) = o;
}

// h1 = bf16(tanh(xpf))   (first recurrent step: h0 = 0; xpf includes b_rec)
__global__ __launch_bounds__(256) void h1f(const float* __restrict__ xpf,
                                           unsigned short* __restrict__ h,
                                           long total) {
  const long idx = ((long)blockIdx.x * 256 + threadIdx.x) * 4;
  if (idx >= total) return;
  const float4 v = *(const float4*)(xpf + idx);
  ushort4 o;
  o.x = f2bf(tanhf(v.x));
  o.y = f2bf(tanhf(v.y));
  o.z = f2bf(tanhf(v.z));
  o.w = f2bf(tanhf(v.w));
  *(ushort4*)(h + idx) = o;
}

// ---------------------------------------------------------------------------
extern "C" void kernel_launch(void* const* d_in, const int* in_sizes, int n_in,
                              void* d_out, int out_size, void* d_ws,
                              size_t ws_size, hipStream_t stream) {
  const float* x = (const float*)d_in[0];
  const float* W_in = (const float*)d_in[1];
  const float* b_in = (const float*)d_in[2];
  const float* W_rec = (const float*)d_in[3];
  const float* b_rec = (const float*)d_in[4];
  const float* W_out = (const float*)d_in[5];
  const float* b_out = (const float*)d_in[6];
  (void)in_sizes; (void)n_in; (void)out_size; (void)ws_size;

  const int B = 4096, DI = 1024, H = 2048, DO = 1000, DOP = 1024;
  const long MB = 1l << 20;

  char* ws = (char*)d_ws;
  unsigned short* Win_bf = (unsigned short*)(ws + 0 * MB);    // [2048][1024] 4MB
  unsigned short* Wrec_bf = (unsigned short*)(ws + 4 * MB);   // [2048][2048] 8MB
  unsigned short* Wout_bf = (unsigned short*)(ws + 12 * MB);  // [1024][2048] 4MB
  unsigned short* x_bf = (unsigned short*)(ws + 16 * MB);     // [4096][1024] 8MB
  float* xpf = (float*)(ws + 24 * MB);                        // [4096][2048] f32 32MB
  // WT region (56..72MB) is DEAD after sigma; h_a aliases it afterwards.
  unsigned short* WT_in_bf = (unsigned short*)(ws + 56 * MB);   // [1024][2048] 4MB
  unsigned short* WT_rec_bf = (unsigned short*)(ws + 60 * MB);  // [2048][2048] 8MB
  unsigned short* WT_out_bf = (unsigned short*)(ws + 68 * MB);  // [2048][1024] 4MB
  unsigned short* h_a = (unsigned short*)(ws + 56 * MB);      // 16MB
  unsigned short* h_b = (unsigned short*)(ws + 72 * MB);      // 16MB
  float* pvec = (float*)(ws + 88 * MB);
  float* tvec = pvec + 5120;
  float* cbuf = tvec + 5120;
  float* scal = cbuf + 5120;

  float* p_in = pvec, *p_rec = pvec + 2048, *p_out = pvec + 4096;
  float* t_in = tvec, *t_rec = tvec + 1024, *t_out = tvec + 3072;

  // 1. bf16 conversions (weights, x) and bf16 transposes (power iteration)
  f32_to_bf16_pad<<<2048, 256, 0, stream>>>(W_in, Win_bf, (long)H * DI, (long)H * DI);
  f32_to_bf16_pad<<<4096, 256, 0, stream>>>(W_rec, Wrec_bf, (long)H * H, (long)H * H);
  f32_to_bf16_pad<<<2048, 256, 0, stream>>>(W_out, Wout_bf, (long)DO * H, (long)DOP * H);
  f32_to_bf16_pad<<<4096, 256, 0, stream>>>(x, x_bf, (long)B * DI, (long)B * DI);
  transpose_pad_b<<<dim3(DI / 32, H / 32), 256, 0, stream>>>(W_in, WT_in_bf, H, DI, H);
  transpose_pad_b<<<dim3(H / 32, H / 32), 256, 0, stream>>>(W_rec, WT_rec_bf, H, H, H);
  transpose_pad_b<<<dim3(H / 32, DOP / 32), 256, 0, stream>>>(W_out, WT_out_bf, DOP, H, DO);

  // 2. Power iteration (bf16 weights, fp32 accum; unnormalized, scale-free)
  init_p<<<20, 256, 0, stream>>>(pvec);
  MatDescB B1a = {WT_in_bf, p_in, t_in, 1024, 2048, 2048};
  MatDescB B1b = {WT_rec_bf, p_rec, t_rec, 2048, 2048, 2048};
  MatDescB B1c = {WT_out_bf, p_out, t_out, 2048, 1024, 1024};
  MatDescB B2a = {Win_bf, t_in, p_in, 2048, 1024, 1024};
  MatDescB B2b = {Wrec_bf, t_rec, p_rec, 2048, 2048, 2048};
  MatDescB B2c = {Wout_bf, t_out, p_out, 1024, 2048, 2048};
  for (int it = 0; it < NSTEPS; ++it) {
    matvec3b<<<1280, 256, 0, stream>>>(B1a, B1b, B1c, 256, 512);
    matvec3b<<<1280, 256, 0, stream>>>(B2a, B2b, B2c, 512, 512);
  }
  matvec3b<<<1280, 256, 0, stream>>>(B1a, B1b, B1c, 256, 512);  // t = W^T u

  // 3. sigma via exact fp32 W: c_i = p_i * (row_i(W) . t); then 1/sigma
  MatDesc sa = {W_in, t_in, cbuf, p_in, 2048, 1024, 1024, 2048};
  MatDesc sb = {W_rec, t_rec, cbuf + 2048, p_rec, 2048, 2048, 2048, 2048};
  MatDesc sc = {W_out, t_out, cbuf + 4096, p_out, 1024, 2048, 2048, 1000};
  matvec3<<<1280, 256, 0, stream>>>(sa, sb, sc, 512, 512);
  finalize_sigma<<<1, 256, 0, stream>>>(pvec, tvec, cbuf, scal);

  // 4. xpf = x @ Win^T * is0 + b_in + b_rec   (f32, exact bias path)
  gemm2ph<0><<<(B / 256) * (H / 128), 512, 0, stream>>>(
      x_bf, Win_bf, H, DI, H / 128, b_in, b_rec, nullptr, scal + 0, xpf,
      nullptr, H);

  // 5. h1 = tanh(xpf); then 29 recurrent GEMM steps ping-pong
  h1f<<<8192, 256, 0, stream>>>(xpf, h_a, (long)B * H);
  const unsigned short* hin = h_a;
  unsigned short* hout = h_b;
  for (int s = 2; s <= NSTEPS; ++s) {
    gemm2ph<1><<<(B / 256) * (H / 128), 512, 0, stream>>>(
        hin, Wrec_bf, H, H, H / 128, nullptr, nullptr, xpf, scal + 1, nullptr,
        hout, H);
    const unsigned short* tmp = hin;
    hin = hout;
    hout = (unsigned short*)tmp;
  }

  // 6. out = h @ Wout^T * is2 + b_out  (N padded to 1024, stores guarded)
  gemm2ph<2><<<(B / 256) * (DOP / 128), 512, 0, stream>>>(
      hin, Wout_bf, DOP, H, DOP / 128, b_out, nullptr, nullptr, scal + 2,
      (float*)d_out, nullptr, DO);
}

// Round 4
// 1885.539 us; speedup vs baseline: 1.4262x; 1.0179x over previous
//
#include <hip/hip_runtime.h>
#include <cstdint>
#include <cstddef>

#define NSTEPS 30

typedef __attribute__((ext_vector_type(4))) float f32x4;
typedef __attribute__((ext_vector_type(8))) short bf16x8;

__device__ __forceinline__ unsigned short f2bf(float f) {
  union { float f; unsigned int u; } v; v.f = f;
  return (unsigned short)((v.u + 0x7FFFu + ((v.u >> 16) & 1u)) >> 16);
}
__device__ __forceinline__ float bf2f(unsigned short u) {
  union { unsigned int u; float f; } v; v.u = ((unsigned int)u) << 16;
  return v.f;
}

__device__ __forceinline__ void gload_lds16(const void* g, void* l) {
  __builtin_amdgcn_global_load_lds(
      (const __attribute__((address_space(1))) unsigned int*)g,
      (__attribute__((address_space(3))) unsigned int*)l, 16, 0, 0);
}

// ---------------------------------------------------------------------------
// 256x128-tile GEMM, BK=64, 3-buffer counted-vmcnt pipeline: C = A @ B^T.
// A [M,K] bf16 row-major, B [N,K] bf16 row-major. 8 waves (4M x 2N),
// per-wave 64x64 output = 4x4 frags of mfma 16x16x32 bf16.
// LDS 144 KiB: A tri-buf [256][64] + B tri-buf [128][64], XOR-swizzled
// (byte ^= (row&7)<<4; inverse-swizzled GLOBAL source + linear
// global_load_lds dest + swizzled ds_read — both-sides rule).
// Schedule per K-tile t: vmcnt(6) [retire tile t's loads; tile t+1 stays in
// flight] -> barrier -> stage tile t+2 into buf[(t+2)%3] -> compute buf[t%3].
// vmcnt never drains to 0 in the main loop (T4).  Hazards:
//  RAW: per-wave vmcnt(6)+barrier => all waves' tile-t loads landed.
//  WAR: stage target buf[(t-1)%3]; its ds_reads (iter t-1) are drained
//       before each wave's barrier arrival (every read feeds an MFMA);
//       sched_barrier(0) pins the stage below the barrier.
// MODE 0: outf[r*N+c] = acc*is + bias[c] + bias2[c]          (xproj, f32)
// MODE 1: outbf[r*N+c] = bf16(tanh(acc*is + xpf[r*N+c]))     (recurrent)
// MODE 2: if c<Nreal: outf[r*Nreal+c] = acc*is + bias[c]     (final out)
// ---------------------------------------------------------------------------
template <int MODE>
__global__ __launch_bounds__(512, 2) void gemm3b(
    const unsigned short* __restrict__ A, const unsigned short* __restrict__ Bm,
    int N, int K, int nbn, const float* __restrict__ bias,
    const float* __restrict__ bias2, const float* __restrict__ xpf,
    const float* __restrict__ inv_sig, float* __restrict__ outf,
    unsigned short* __restrict__ outbf, int Nreal) {
  __shared__ short lds[73728];  // 144 KiB: A 3x16384, B 3x8192 (shorts)
  const int t = threadIdx.x, w = t >> 6, l = t & 63;
  const int wm = w >> 1, wn = w & 1;
  const int bm = blockIdx.x / nbn, bn = blockIdx.x % nbn;
  const int row0 = bm << 8, col0 = bn << 7;
  const int NKT = K >> 6;

  f32x4 acc[4][4];
#pragma unroll
  for (int i = 0; i < 4; ++i)
#pragma unroll
    for (int j = 0; j < 4; ++j) acc[i][j] = (f32x4){0.f, 0.f, 0.f, 0.f};

  // Stage K-tile `tile` into buffer `buf` (0..2). 6 gload_lds16 per thread.
  // Dest linear: row*128B + (l&7)*16B. Source k pre-swizzled by ((row&7)<<4)B.
#define STAGE(tile, buf)                                                      \
  do {                                                                        \
    const int kt_ = (tile) << 6;                                              \
    const int kb_ = (((l & 7) ^ (l >> 3)) << 4) >> 1; /* shorts */            \
    const int rl_ = w * 8 + (l >> 3);                                         \
    _Pragma("unroll") for (int j_ = 0; j_ < 4; ++j_) {                        \
      gload_lds16(A + (size_t)(row0 + j_ * 64 + rl_) * K + kt_ + kb_,         \
                  lds + (buf) * 16384 + j_ * 4096 + w * 512);                 \
    }                                                                         \
    _Pragma("unroll") for (int j_ = 0; j_ < 2; ++j_) {                        \
      gload_lds16(Bm + (size_t)(col0 + j_ * 64 + rl_) * K + kt_ + kb_,        \
                  lds + 49152 + (buf) * 8192 + j_ * 4096 + w * 512);          \
    }                                                                         \
  } while (0)

  STAGE(0, 0);
  STAGE(1, 1);

  const int ar = l & 15;
  const int swzk = (l & 7) << 4;               // bytes
  const int klo = (l >> 4) << 4;               // bytes
  const int kb0 = ((klo ^ swzk) >> 1);         // shorts, k-slice 0
  const int kb1 = (((klo + 64) ^ swzk) >> 1);  // shorts, k-slice 1

  int cur = 0;
  for (int kt = 0; kt < NKT; ++kt) {
    if (kt + 1 < NKT) {
      asm volatile("s_waitcnt vmcnt(6)" ::: "memory");
    } else {
      asm volatile("s_waitcnt vmcnt(0)" ::: "memory");
    }
    __builtin_amdgcn_s_barrier();
    __builtin_amdgcn_sched_barrier(0);
    if (kt + 2 < NKT) {
      const int stg = (cur >= 1) ? cur - 1 : cur + 2;  // (cur+2)%3
      STAGE(kt + 2, stg);
    }

    bf16x8 av[4][2], bv[4][2];
    const int abase = cur * 16384 + (wm * 64 + ar) * 64;
    const int bbase = 49152 + cur * 8192 + (wn * 64 + ar) * 64;
#pragma unroll
    for (int fm = 0; fm < 4; ++fm) {
      av[fm][0] = *(const bf16x8*)(lds + abase + fm * 1024 + kb0);
      av[fm][1] = *(const bf16x8*)(lds + abase + fm * 1024 + kb1);
    }
#pragma unroll
    for (int fn = 0; fn < 4; ++fn) {
      bv[fn][0] = *(const bf16x8*)(lds + bbase + fn * 1024 + kb0);
      bv[fn][1] = *(const bf16x8*)(lds + bbase + fn * 1024 + kb1);
    }
#pragma unroll
    for (int s = 0; s < 2; ++s)
#pragma unroll
      for (int fm = 0; fm < 4; ++fm)
#pragma unroll
        for (int fn = 0; fn < 4; ++fn)
          acc[fm][fn] = __builtin_amdgcn_mfma_f32_16x16x32_bf16(
              av[fm][s], bv[fn][s], acc[fm][fn], 0, 0, 0);
    cur = (cur == 2) ? 0 : cur + 1;
  }
#undef STAGE

  const float is = inv_sig[0];
#pragma unroll
  for (int fm = 0; fm < 4; ++fm) {
#pragma unroll
    for (int fn = 0; fn < 4; ++fn) {
      const int c = col0 + wn * 64 + fn * 16 + ar;
#pragma unroll
      for (int q = 0; q < 4; ++q) {
        const int r = row0 + wm * 64 + fm * 16 + (l >> 4) * 4 + q;
        const float v = acc[fm][fn][q] * is;
        if (MODE == 0) {
          outf[(size_t)r * N + c] = v + bias[c] + bias2[c];
        } else if (MODE == 1) {
          outbf[(size_t)r * N + c] = f2bf(tanhf(v + xpf[(size_t)r * N + c]));
        } else {
          if (c < Nreal) outf[(size_t)r * Nreal + c] = v + bias[c];
        }
      }
    }
  }
}

// ---------------------------------------------------------------------------
// Tiled transpose f32 -> bf16 with row padding: out[C][Rpad] = bf16(in^T)
// ---------------------------------------------------------------------------
__global__ __launch_bounds__(256) void transpose_pad_b(
    const float* __restrict__ in, unsigned short* __restrict__ out, int Rpad,
    int C, int Rreal) {
  __shared__ float tile[32][33];
  const int c0 = blockIdx.x * 32, r0 = blockIdx.y * 32;
  const int tx = threadIdx.x & 31, ty = threadIdx.x >> 5;
  for (int i = ty; i < 32; i += 8) {
    const int r = r0 + i;
    tile[i][tx] = (r < Rreal) ? in[(size_t)r * C + (c0 + tx)] : 0.f;
  }
  __syncthreads();
  for (int i = ty; i < 32; i += 8) {
    out[(size_t)(c0 + i) * Rpad + (r0 + tx)] = f2bf(tile[tx][i]);
  }
}

// fp32 matvec (sigma pass, exact weights): y[r] = mulv[r] * (row_r(M) . x)
struct MatDesc {
  const float* M;
  const float* x;
  float* y;
  const float* mulv;
  int rows, ld, dot, rreal;
};

__global__ __launch_bounds__(256) void matvec3(MatDesc d0, MatDesc d1,
                                               MatDesc d2, int n0, int n1) {
  int b = blockIdx.x;
  MatDesc d;
  if (b < n0) d = d0;
  else if (b < n0 + n1) { d = d1; b -= n0; }
  else { d = d2; b -= n0 + n1; }
  const int w = threadIdx.x >> 6, l = threadIdx.x & 63;
  const int r = b * 4 + w;
  if (r >= d.rows) return;
  float s = 0.f;
  if (r < d.rreal) {
    const float* Mr = d.M + (size_t)r * d.ld;
#pragma unroll 8
    for (int j = l * 4; j < d.dot; j += 256) {
      const float4 mv = *(const float4*)(Mr + j);
      const float4 xv = *(const float4*)(d.x + j);
      s += mv.x * xv.x + mv.y * xv.y + mv.z * xv.z + mv.w * xv.w;
    }
  }
#pragma unroll
  for (int off = 32; off; off >>= 1) s += __shfl_down(s, off, 64);
  if (l == 0) d.y[r] = (d.mulv ? d.mulv[r] : 1.f) * s;
}

// bf16 matvec (power-iteration passes): y[r] = row_r(M) . x
struct MatDescB {
  const unsigned short* M;
  const float* x;
  float* y;
  int rows, ld, dot;
};

__global__ __launch_bounds__(256) void matvec3b(MatDescB d0, MatDescB d1,
                                                MatDescB d2, int n0, int n1) {
  int b = blockIdx.x;
  MatDescB d;
  if (b < n0) d = d0;
  else if (b < n0 + n1) { d = d1; b -= n0; }
  else { d = d2; b -= n0 + n1; }
  const int w = threadIdx.x >> 6, l = threadIdx.x & 63;
  const int r = b * 4 + w;
  if (r >= d.rows) return;
  const unsigned short* Mr = d.M + (size_t)r * d.ld;
  float s = 0.f;
#pragma unroll 4
  for (int j = l * 8; j < d.dot; j += 512) {
    const bf16x8 mv = *(const bf16x8*)(Mr + j);
    const float4 xa = *(const float4*)(d.x + j);
    const float4 xb = *(const float4*)(d.x + j + 4);
    s += bf2f((unsigned short)mv[0]) * xa.x + bf2f((unsigned short)mv[1]) * xa.y +
         bf2f((unsigned short)mv[2]) * xa.z + bf2f((unsigned short)mv[3]) * xa.w +
         bf2f((unsigned short)mv[4]) * xb.x + bf2f((unsigned short)mv[5]) * xb.y +
         bf2f((unsigned short)mv[6]) * xb.z + bf2f((unsigned short)mv[7]) * xb.w;
  }
#pragma unroll
  for (int off = 32; off; off >>= 1) s += __shfl_down(s, off, 64);
  if (l == 0) d.y[r] = s;
}

__global__ void init_p(float* p) {
  const int i = blockIdx.x * 256 + threadIdx.x;
  if (i < 5120) p[i] = (i < 5096) ? 1.f : 0.f;  // p_out rows 1000..1023 = 0
}

// Single-block deterministic reductions -> inv_sigma[3]
__global__ __launch_bounds__(256) void finalize_sigma(
    const float* __restrict__ p, const float* __restrict__ t,
    const float* __restrict__ cb, float* __restrict__ scal) {
  __shared__ float red[256];
  __shared__ float sres[9];
  const int segs[9][2] = {{0, 2048},    {2048, 2048}, {4096, 1024},
                          {0, 1024},    {1024, 2048}, {3072, 2048},
                          {0, 2048},    {2048, 2048}, {4096, 1024}};
  const float* bases[3] = {p, t, cb};
  for (int s = 0; s < 9; ++s) {
    const float* src = bases[s / 3] + segs[s][0];
    const int len = segs[s][1];
    float acc = 0.f;
    for (int i = threadIdx.x; i < len; i += 256) {
      const float v = src[i];
      acc += (s < 6) ? v * v : v;
    }
    red[threadIdx.x] = acc;
    __syncthreads();
    for (int st = 128; st; st >>= 1) {
      if (threadIdx.x < st) red[threadIdx.x] += red[threadIdx.x + st];
      __syncthreads();
    }
    if (threadIdx.x == 0) sres[s] = red[0];
    __syncthreads();
  }
  if (threadIdx.x == 0) {
    const float eps = 1e-12f;
    for (int m = 0; m < 3; ++m) {
      const float np = sqrtf(sres[m]);
      const float nt = sqrtf(sres[3 + m]);
      const float sig = sres[6 + m] / ((np + eps) * (nt + eps));
      scal[m] = 1.0f / sig;
    }
  }
}

// fp32 -> bf16 with trailing zero pad
__global__ __launch_bounds__(256) void f32_to_bf16_pad(
    const float* __restrict__ src, unsigned short* __restrict__ dst,
    long realTotal, long total) {
  const long idx = ((long)blockIdx.x * 256 + threadIdx.x) * 4;
  if (idx >= total) return;
  ushort4 o;
  if (idx < realTotal) {
    const float4 v = *(const float4*)(src + idx);
    o.x = f2bf(v.x); o.y = f2bf(v.y); o.z = f2bf(v.z); o.w = f2bf(v.w);
  } else {
    o.x = o.y = o.z = o.w = 0;
  }
  *(ushort4*)(dst + idx) = o;
}

// h1 = bf16(tanh(xpf))   (first recurrent step: h0 = 0; xpf includes b_rec)
__global__ __launch_bounds__(256) void h1f(const float* __restrict__ xpf,
                                           unsigned short* __restrict__ h,
                                           long total) {
  const long idx = ((long)blockIdx.x * 256 + threadIdx.x) * 4;
  if (idx >= total) return;
  const float4 v = *(const float4*)(xpf + idx);
  ushort4 o;
  o.x = f2bf(tanhf(v.x));
  o.y = f2bf(tanhf(v.y));
  o.z = f2bf(tanhf(v.z));
  o.w = f2bf(tanhf(v.w));
  *(ushort4*)(h + idx) = o;
}

// ---------------------------------------------------------------------------
extern "C" void kernel_launch(void* const* d_in, const int* in_sizes, int n_in,
                              void* d_out, int out_size, void* d_ws,
                              size_t ws_size, hipStream_t stream) {
  const float* x = (const float*)d_in[0];
  const float* W_in = (const float*)d_in[1];
  const float* b_in = (const float*)d_in[2];
  const float* W_rec = (const float*)d_in[3];
  const float* b_rec = (const float*)d_in[4];
  const float* W_out = (const float*)d_in[5];
  const float* b_out = (const float*)d_in[6];
  (void)in_sizes; (void)n_in; (void)out_size; (void)ws_size;

  const int B = 4096, DI = 1024, H = 2048, DO = 1000, DOP = 1024;
  const long MB = 1l << 20;

  char* ws = (char*)d_ws;
  unsigned short* Win_bf = (unsigned short*)(ws + 0 * MB);    // [2048][1024] 4MB
  unsigned short* Wrec_bf = (unsigned short*)(ws + 4 * MB);   // [2048][2048] 8MB
  unsigned short* Wout_bf = (unsigned short*)(ws + 12 * MB);  // [1024][2048] 4MB
  unsigned short* x_bf = (unsigned short*)(ws + 16 * MB);     // [4096][1024] 8MB
  float* xpf = (float*)(ws + 24 * MB);                        // [4096][2048] f32 32MB
  // WT region (56..72MB) is DEAD after sigma; h_a aliases it afterwards.
  unsigned short* WT_in_bf = (unsigned short*)(ws + 56 * MB);   // [1024][2048] 4MB
  unsigned short* WT_rec_bf = (unsigned short*)(ws + 60 * MB);  // [2048][2048] 8MB
  unsigned short* WT_out_bf = (unsigned short*)(ws + 68 * MB);  // [2048][1024] 4MB
  unsigned short* h_a = (unsigned short*)(ws + 56 * MB);      // 16MB
  unsigned short* h_b = (unsigned short*)(ws + 72 * MB);      // 16MB
  float* pvec = (float*)(ws + 88 * MB);
  float* tvec = pvec + 5120;
  float* cbuf = tvec + 5120;
  float* scal = cbuf + 5120;

  float* p_in = pvec, *p_rec = pvec + 2048, *p_out = pvec + 4096;
  float* t_in = tvec, *t_rec = tvec + 1024, *t_out = tvec + 3072;

  // 1. bf16 conversions (weights, x) and bf16 transposes (power iteration)
  f32_to_bf16_pad<<<2048, 256, 0, stream>>>(W_in, Win_bf, (long)H * DI, (long)H * DI);
  f32_to_bf16_pad<<<4096, 256, 0, stream>>>(W_rec, Wrec_bf, (long)H * H, (long)H * H);
  f32_to_bf16_pad<<<2048, 256, 0, stream>>>(W_out, Wout_bf, (long)DO * H, (long)DOP * H);
  f32_to_bf16_pad<<<4096, 256, 0, stream>>>(x, x_bf, (long)B * DI, (long)B * DI);
  transpose_pad_b<<<dim3(DI / 32, H / 32), 256, 0, stream>>>(W_in, WT_in_bf, H, DI, H);
  transpose_pad_b<<<dim3(H / 32, H / 32), 256, 0, stream>>>(W_rec, WT_rec_bf, H, H, H);
  transpose_pad_b<<<dim3(H / 32, DOP / 32), 256, 0, stream>>>(W_out, WT_out_bf, DOP, H, DO);

  // 2. Power iteration (bf16 weights, fp32 accum; unnormalized, scale-free)
  init_p<<<20, 256, 0, stream>>>(pvec);
  MatDescB B1a = {WT_in_bf, p_in, t_in, 1024, 2048, 2048};
  MatDescB B1b = {WT_rec_bf, p_rec, t_rec, 2048, 2048, 2048};
  MatDescB B1c = {WT_out_bf, p_out, t_out, 2048, 1024, 1024};
  MatDescB B2a = {Win_bf, t_in, p_in, 2048, 1024, 1024};
  MatDescB B2b = {Wrec_bf, t_rec, p_rec, 2048, 2048, 2048};
  MatDescB B2c = {Wout_bf, t_out, p_out, 1024, 2048, 2048};
  for (int it = 0; it < NSTEPS; ++it) {
    matvec3b<<<1280, 256, 0, stream>>>(B1a, B1b, B1c, 256, 512);
    matvec3b<<<1280, 256, 0, stream>>>(B2a, B2b, B2c, 512, 512);
  }
  matvec3b<<<1280, 256, 0, stream>>>(B1a, B1b, B1c, 256, 512);  // t = W^T u

  // 3. sigma via exact fp32 W: c_i = p_i * (row_i(W) . t); then 1/sigma
  MatDesc sa = {W_in, t_in, cbuf, p_in, 2048, 1024, 1024, 2048};
  MatDesc sb = {W_rec, t_rec, cbuf + 2048, p_rec, 2048, 2048, 2048, 2048};
  MatDesc sc = {W_out, t_out, cbuf + 4096, p_out, 1024, 2048, 2048, 1000};
  matvec3<<<1280, 256, 0, stream>>>(sa, sb, sc, 512, 512);
  finalize_sigma<<<1, 256, 0, stream>>>(pvec, tvec, cbuf, scal);

  // 4. xpf = x @ Win^T * is0 + b_in + b_rec   (f32, exact bias path)
  gemm3b<0><<<(B / 256) * (H / 128), 512, 0, stream>>>(
      x_bf, Win_bf, H, DI, H / 128, b_in, b_rec, nullptr, scal + 0, xpf,
      nullptr, H);

  // 5. h1 = tanh(xpf); then 29 recurrent GEMM steps ping-pong
  h1f<<<8192, 256, 0, stream>>>(xpf, h_a, (long)B * H);
  const unsigned short* hin = h_a;
  unsigned short* hout = h_b;
  for (int s = 2; s <= NSTEPS; ++s) {
    gemm3b<1><<<(B / 256) * (H / 128), 512, 0, stream>>>(
        hin, Wrec_bf, H, H, H / 128, nullptr, nullptr, xpf, scal + 1, nullptr,
        hout, H);
    const unsigned short* tmp = hin;
    hin = hout;
    hout = (unsigned short*)tmp;
  }

  // 6. out = h @ Wout^T * is2 + b_out  (N padded to 1024, stores guarded)
  gemm3b<2><<<(B / 256) * (DOP / 128), 512, 0, stream>>>(
      hin, Wout_bf, DOP, H, DOP / 128, b_out, nullptr, nullptr, scal + 2,
      (float*)d_out, nullptr, DO);
}

// Round 5
// 1810.723 us; speedup vs baseline: 1.4851x; 1.0413x over previous
//
#include <hip/hip_runtime.h>
#include <cstdint>
#include <cstddef>

#define NSTEPS 30

typedef __attribute__((ext_vector_type(4))) float f32x4;
typedef __attribute__((ext_vector_type(8))) short bf16x8;

__device__ __forceinline__ unsigned short f2bf(float f) {
  union { float f; unsigned int u; } v; v.f = f;
  return (unsigned short)((v.u + 0x7FFFu + ((v.u >> 16) & 1u)) >> 16);
}
__device__ __forceinline__ float bf2f(unsigned short u) {
  union { unsigned int u; float f; } v; v.u = ((unsigned int)u) << 16;
  return v.f;
}

__device__ __forceinline__ void gload_lds16(const void* g, void* l) {
  __builtin_amdgcn_global_load_lds(
      (const __attribute__((address_space(1))) unsigned int*)g,
      (__attribute__((address_space(3))) unsigned int*)l, 16, 0, 0);
}

// ---------------------------------------------------------------------------
// 256x128-tile GEMM, BK=64, phase-split pipeline (m201 cadence): C = A @ B^T.
// 8 waves (4M x 2N), per-wave 64x64 = 4x4 frags of mfma 16x16x32 bf16.
// LDS 144 KiB: A tri-buf [256][64] + B tri-buf [128][64], XOR-swizzled
// (byte ^= (row&7)<<4; inverse-swizzled GLOBAL source + linear
// global_load_lds dest + swizzled ds_read).
// Per K-tile t (buf c=t%3, staging tile t+2 into (t+2)%3):
//  phA: stage A(t+2) [4 loads]; ds_read k-slice0 (8x b128); barrier;
//       lgkm0; setprio1; 16 MFMA; setprio0; barrier.
//  phB: stage B(t+2) [2 loads]; ds_read k-slice1; vmcnt(6) [retire tile t+1,
//       keep t+2 in flight; vmcnt(0) only at tail]; barrier; lgkm0;
//       setprio1; 16 MFMA; setprio0; barrier.
// Hazards: RAW — tile t retired by iter t-1 phB vmcnt+barrier before iter t
// reads. WAR — stage target buf (t-1)%3 fully consumed (lgkm0 before MFMA)
// before iter t-1's closing barrier; stages issue after it.
// XCD swizzle: xcd=bid&7 -> 4x2 XCD grid; per-XCD (nbm/4)x(nbn/2) region.
// MODE 0: xpb[r*N+c] = bf16(acc*is + bias[c] + bias2[c])
// MODE 1: outbf[r*N+c] = bf16(tanh(acc*is + xpb[r*N+c]))
// MODE 2: if c<Nreal: outf[r*Nreal+c] = acc*is + bias[c]
// ---------------------------------------------------------------------------
template <int MODE>
__global__ __launch_bounds__(512, 2) void gemm8p(
    const unsigned short* __restrict__ A, const unsigned short* __restrict__ Bm,
    int N, int K, int nbm, int nbn, const float* __restrict__ bias,
    const float* __restrict__ bias2, const unsigned short* __restrict__ xpb,
    const float* __restrict__ inv_sig, float* __restrict__ outf,
    unsigned short* __restrict__ outbf, int Nreal) {
  __shared__ short lds[73728];  // 144 KiB: A 3x16384, B 3x8192 (shorts)
  const int t = threadIdx.x, w = t >> 6, l = t & 63;
  const int wm = w >> 1, wn = w & 1;
  const int nbn2 = nbn >> 1, nbm4 = nbm >> 2;
  const int xcd = blockIdx.x & 7, q = blockIdx.x >> 3;
  const int bm = (xcd >> 1) * nbm4 + q / nbn2;
  const int bn = (xcd & 1) * nbn2 + q % nbn2;
  const int row0 = bm << 8, col0 = bn << 7;
  const int NKT = K >> 6;

  f32x4 acc[4][4];
#pragma unroll
  for (int i = 0; i < 4; ++i)
#pragma unroll
    for (int j = 0; j < 4; ++j) acc[i][j] = (f32x4){0.f, 0.f, 0.f, 0.f};

// Stage units. Dest linear: row*128B + (l&7)*16B; src k pre-swizzled.
#define SA2(tile, buf, h)                                                     \
  do {                                                                        \
    const int kt_ = (tile) << 6;                                              \
    const int kb_ = (((l & 7) ^ (l >> 3)) << 4) >> 1; /* shorts */            \
    const int rl_ = w * 8 + (l >> 3);                                         \
    _Pragma("unroll") for (int j_ = 2 * (h); j_ < 2 * (h) + 2; ++j_) {        \
      gload_lds16(A + (size_t)(row0 + j_ * 64 + rl_) * K + kt_ + kb_,         \
                  lds + (buf) * 16384 + j_ * 4096 + w * 512);                 \
    }                                                                         \
  } while (0)
#define SB2(tile, buf)                                                        \
  do {                                                                        \
    const int kt_ = (tile) << 6;                                              \
    const int kb_ = (((l & 7) ^ (l >> 3)) << 4) >> 1;                         \
    const int rl_ = w * 8 + (l >> 3);                                         \
    _Pragma("unroll") for (int j_ = 0; j_ < 2; ++j_) {                        \
      gload_lds16(Bm + (size_t)(col0 + j_ * 64 + rl_) * K + kt_ + kb_,        \
                  lds + 49152 + (buf) * 8192 + j_ * 4096 + w * 512);          \
    }                                                                         \
  } while (0)

#define PH_READS(kb)                                                          \
  _Pragma("unroll") for (int f_ = 0; f_ < 4; ++f_) {                          \
    av[f_] = *(const bf16x8*)(lds + abase + f_ * 1024 + (kb));                \
    bv[f_] = *(const bf16x8*)(lds + bbase + f_ * 1024 + (kb));                \
  }

#define PH_MFMA()                                                             \
  __builtin_amdgcn_s_setprio(1);                                              \
  _Pragma("unroll") for (int fm_ = 0; fm_ < 4; ++fm_)                         \
      _Pragma("unroll") for (int fn_ = 0; fn_ < 4; ++fn_) acc[fm_][fn_] =     \
      __builtin_amdgcn_mfma_f32_16x16x32_bf16(av[fm_], bv[fn_],               \
                                              acc[fm_][fn_], 0, 0, 0);        \
  __builtin_amdgcn_s_setprio(0);

#define BAR_IN()                                                              \
  __builtin_amdgcn_sched_barrier(0);                                          \
  __builtin_amdgcn_s_barrier();                                               \
  asm volatile("s_waitcnt lgkmcnt(0)" ::: "memory");                          \
  __builtin_amdgcn_sched_barrier(0)

#define BAR_OUT()                                                             \
  __builtin_amdgcn_sched_barrier(0);                                          \
  __builtin_amdgcn_s_barrier();                                               \
  __builtin_amdgcn_sched_barrier(0)

  // Prologue: tile0 -> buf0, tile1 -> buf1 (12 loads); retire tile0 only.
  SA2(0, 0, 0); SA2(0, 0, 1); SB2(0, 0);
  SA2(1, 1, 0); SA2(1, 1, 1); SB2(1, 1);
  asm volatile("s_waitcnt vmcnt(6)" ::: "memory");
  BAR_OUT();

  const int ar = l & 15;
  const int swzk = (l & 7) << 4;               // bytes
  const int klo = (l >> 4) << 4;               // bytes
  const int kb0 = ((klo ^ swzk) >> 1);         // shorts, k-slice 0
  const int kb1 = (((klo + 64) ^ swzk) >> 1);  // shorts, k-slice 1

  int cur = 0;
  for (int kt = 0; kt < NKT; ++kt) {
    const int s2 = (cur >= 1) ? cur - 1 : cur + 2;  // (cur+2)%3
    const int abase = cur * 16384 + (wm * 64 + ar) * 64;
    const int bbase = 49152 + cur * 8192 + (wn * 64 + ar) * 64;
    const bool pre = (kt + 2 < NKT);
    bf16x8 av[4], bv[4];
    // ---- phase A: k-slice 0
    if (pre) { SA2(kt + 2, s2, 0); SA2(kt + 2, s2, 1); }
    PH_READS(kb0);
    BAR_IN();
    PH_MFMA();
    BAR_OUT();
    // ---- phase B: k-slice 1
    if (pre) SB2(kt + 2, s2);
    PH_READS(kb1);
    if (pre) {
      asm volatile("s_waitcnt vmcnt(6)" ::: "memory");
    } else {
      asm volatile("s_waitcnt vmcnt(0)" ::: "memory");
    }
    BAR_IN();
    PH_MFMA();
    BAR_OUT();
    cur = (cur == 2) ? 0 : cur + 1;
  }
  asm volatile("s_waitcnt vmcnt(0)" ::: "memory");  // safety drain
#undef SA2
#undef SB2
#undef PH_READS
#undef PH_MFMA
#undef BAR_IN
#undef BAR_OUT

  const float is = inv_sig[0];
#pragma unroll
  for (int fm = 0; fm < 4; ++fm) {
#pragma unroll
    for (int fn = 0; fn < 4; ++fn) {
      const int c = col0 + wn * 64 + fn * 16 + ar;
#pragma unroll
      for (int qq = 0; qq < 4; ++qq) {
        const int r = row0 + wm * 64 + fm * 16 + (l >> 4) * 4 + qq;
        const float v = acc[fm][fn][qq] * is;
        if (MODE == 0) {
          outbf[(size_t)r * N + c] = f2bf(v + bias[c] + bias2[c]);
        } else if (MODE == 1) {
          outbf[(size_t)r * N + c] =
              f2bf(tanhf(v + bf2f(xpb[(size_t)r * N + c])));
        } else {
          if (c < Nreal) outf[(size_t)r * Nreal + c] = v + bias[c];
        }
      }
    }
  }
}

// ---------------------------------------------------------------------------
// Tiled transpose f32 -> bf16 with row padding: out[C][Rpad] = bf16(in^T)
// ---------------------------------------------------------------------------
__global__ __launch_bounds__(256) void transpose_pad_b(
    const float* __restrict__ in, unsigned short* __restrict__ out, int Rpad,
    int C, int Rreal) {
  __shared__ float tile[32][33];
  const int c0 = blockIdx.x * 32, r0 = blockIdx.y * 32;
  const int tx = threadIdx.x & 31, ty = threadIdx.x >> 5;
  for (int i = ty; i < 32; i += 8) {
    const int r = r0 + i;
    tile[i][tx] = (r < Rreal) ? in[(size_t)r * C + (c0 + tx)] : 0.f;
  }
  __syncthreads();
  for (int i = ty; i < 32; i += 8) {
    out[(size_t)(c0 + i) * Rpad + (r0 + tx)] = f2bf(tile[tx][i]);
  }
}

// fp32 matvec (sigma pass, exact weights): y[r] = mulv[r] * (row_r(M) . x)
struct MatDesc {
  const float* M;
  const float* x;
  float* y;
  const float* mulv;
  int rows, ld, dot, rreal;
};

__global__ __launch_bounds__(256) void matvec3(MatDesc d0, MatDesc d1,
                                               MatDesc d2, int n0, int n1) {
  int b = blockIdx.x;
  MatDesc d;
  if (b < n0) d = d0;
  else if (b < n0 + n1) { d = d1; b -= n0; }
  else { d = d2; b -= n0 + n1; }
  const int w = threadIdx.x >> 6, l = threadIdx.x & 63;
  const int r = b * 4 + w;
  if (r >= d.rows) return;
  float s = 0.f;
  if (r < d.rreal) {
    const float* Mr = d.M + (size_t)r * d.ld;
#pragma unroll 8
    for (int j = l * 4; j < d.dot; j += 256) {
      const float4 mv = *(const float4*)(Mr + j);
      const float4 xv = *(const float4*)(d.x + j);
      s += mv.x * xv.x + mv.y * xv.y + mv.z * xv.z + mv.w * xv.w;
    }
  }
#pragma unroll
  for (int off = 32; off; off >>= 1) s += __shfl_down(s, off, 64);
  if (l == 0) d.y[r] = (d.mulv ? d.mulv[r] : 1.f) * s;
}

// bf16 matvec (power-iteration passes): y[r] = row_r(M) . x
struct MatDescB {
  const unsigned short* M;
  const float* x;
  float* y;
  int rows, ld, dot;
};

__global__ __launch_bounds__(256) void matvec3b(MatDescB d0, MatDescB d1,
                                                MatDescB d2, int n0, int n1) {
  int b = blockIdx.x;
  MatDescB d;
  if (b < n0) d = d0;
  else if (b < n0 + n1) { d = d1; b -= n0; }
  else { d = d2; b -= n0 + n1; }
  const int w = threadIdx.x >> 6, l = threadIdx.x & 63;
  const int r = b * 4 + w;
  if (r >= d.rows) return;
  const unsigned short* Mr = d.M + (size_t)r * d.ld;
  float s = 0.f;
#pragma unroll 4
  for (int j = l * 8; j < d.dot; j += 512) {
    const bf16x8 mv = *(const bf16x8*)(Mr + j);
    const float4 xa = *(const float4*)(d.x + j);
    const float4 xb = *(const float4*)(d.x + j + 4);
    s += bf2f((unsigned short)mv[0]) * xa.x + bf2f((unsigned short)mv[1]) * xa.y +
         bf2f((unsigned short)mv[2]) * xa.z + bf2f((unsigned short)mv[3]) * xa.w +
         bf2f((unsigned short)mv[4]) * xb.x + bf2f((unsigned short)mv[5]) * xb.y +
         bf2f((unsigned short)mv[6]) * xb.z + bf2f((unsigned short)mv[7]) * xb.w;
  }
#pragma unroll
  for (int off = 32; off; off >>= 1) s += __shfl_down(s, off, 64);
  if (l == 0) d.y[r] = s;
}

__global__ void init_p(float* p) {
  const int i = blockIdx.x * 256 + threadIdx.x;
  if (i < 5120) p[i] = (i < 5096) ? 1.f : 0.f;  // p_out rows 1000..1023 = 0
}

// Single-block deterministic reductions -> inv_sigma[3]
__global__ __launch_bounds__(256) void finalize_sigma(
    const float* __restrict__ p, const float* __restrict__ t,
    const float* __restrict__ cb, float* __restrict__ scal) {
  __shared__ float red[256];
  __shared__ float sres[9];
  const int segs[9][2] = {{0, 2048},    {2048, 2048}, {4096, 1024},
                          {0, 1024},    {1024, 2048}, {3072, 2048},
                          {0, 2048},    {2048, 2048}, {4096, 1024}};
  const float* bases[3] = {p, t, cb};
  for (int s = 0; s < 9; ++s) {
    const float* src = bases[s / 3] + segs[s][0];
    const int len = segs[s][1];
    float acc = 0.f;
    for (int i = threadIdx.x; i < len; i += 256) {
      const float v = src[i];
      acc += (s < 6) ? v * v : v;
    }
    red[threadIdx.x] = acc;
    __syncthreads();
    for (int st = 128; st; st >>= 1) {
      if (threadIdx.x < st) red[threadIdx.x] += red[threadIdx.x + st];
      __syncthreads();
    }
    if (threadIdx.x == 0) sres[s] = red[0];
    __syncthreads();
  }
  if (threadIdx.x == 0) {
    const float eps = 1e-12f;
    for (int m = 0; m < 3; ++m) {
      const float np = sqrtf(sres[m]);
      const float nt = sqrtf(sres[3 + m]);
      const float sig = sres[6 + m] / ((np + eps) * (nt + eps));
      scal[m] = 1.0f / sig;
    }
  }
}

// fp32 -> bf16 with trailing zero pad
__global__ __launch_bounds__(256) void f32_to_bf16_pad(
    const float* __restrict__ src, unsigned short* __restrict__ dst,
    long realTotal, long total) {
  const long idx = ((long)blockIdx.x * 256 + threadIdx.x) * 4;
  if (idx >= total) return;
  ushort4 o;
  if (idx < realTotal) {
    const float4 v = *(const float4*)(src + idx);
    o.x = f2bf(v.x); o.y = f2bf(v.y); o.z = f2bf(v.z); o.w = f2bf(v.w);
  } else {
    o.x = o.y = o.z = o.w = 0;
  }
  *(ushort4*)(dst + idx) = o;
}

// h1 = bf16(tanh(xpb))   (first recurrent step: h0 = 0; xpb includes biases)
__global__ __launch_bounds__(256) void h1b(const unsigned short* __restrict__ xpb,
                                           unsigned short* __restrict__ h,
                                           long total) {
  const long idx = ((long)blockIdx.x * 256 + threadIdx.x) * 8;
  if (idx >= total) return;
  const bf16x8 v = *(const bf16x8*)(xpb + idx);
  bf16x8 o;
#pragma unroll
  for (int k = 0; k < 8; ++k)
    o[k] = (short)f2bf(tanhf(bf2f((unsigned short)v[k])));
  *(bf16x8*)(h + idx) = o;
}

// ---------------------------------------------------------------------------
extern "C" void kernel_launch(void* const* d_in, const int* in_sizes, int n_in,
                              void* d_out, int out_size, void* d_ws,
                              size_t ws_size, hipStream_t stream) {
  const float* x = (const float*)d_in[0];
  const float* W_in = (const float*)d_in[1];
  const float* b_in = (const float*)d_in[2];
  const float* W_rec = (const float*)d_in[3];
  const float* b_rec = (const float*)d_in[4];
  const float* W_out = (const float*)d_in[5];
  const float* b_out = (const float*)d_in[6];
  (void)in_sizes; (void)n_in; (void)out_size; (void)ws_size;

  const int B = 4096, DI = 1024, H = 2048, DO = 1000, DOP = 1024;
  const long MB = 1l << 20;

  char* ws = (char*)d_ws;
  unsigned short* Win_bf = (unsigned short*)(ws + 0 * MB);    // [2048][1024] 4MB
  unsigned short* Wrec_bf = (unsigned short*)(ws + 4 * MB);   // [2048][2048] 8MB
  unsigned short* Wout_bf = (unsigned short*)(ws + 12 * MB);  // [1024][2048] 4MB
  unsigned short* x_bf = (unsigned short*)(ws + 16 * MB);     // [4096][1024] 8MB
  unsigned short* xpb = (unsigned short*)(ws + 24 * MB);      // [4096][2048] 16MB
  // WT region (40..56MB) is DEAD after finalize_sigma; h_a aliases it.
  unsigned short* WT_in_bf = (unsigned short*)(ws + 40 * MB);   // 4MB
  unsigned short* WT_rec_bf = (unsigned short*)(ws + 44 * MB);  // 8MB
  unsigned short* WT_out_bf = (unsigned short*)(ws + 52 * MB);  // 4MB
  unsigned short* h_a = (unsigned short*)(ws + 40 * MB);      // 16MB
  unsigned short* h_b = (unsigned short*)(ws + 56 * MB);      // 16MB
  float* pvec = (float*)(ws + 72 * MB);
  float* tvec = pvec + 5120;
  float* cbuf = tvec + 5120;
  float* scal = cbuf + 5120;

  float* p_in = pvec, *p_rec = pvec + 2048, *p_out = pvec + 4096;
  float* t_in = tvec, *t_rec = tvec + 1024, *t_out = tvec + 3072;

  // 1. bf16 conversions (weights, x) and bf16 transposes (power iteration)
  f32_to_bf16_pad<<<2048, 256, 0, stream>>>(W_in, Win_bf, (long)H * DI, (long)H * DI);
  f32_to_bf16_pad<<<4096, 256, 0, stream>>>(W_rec, Wrec_bf, (long)H * H, (long)H * H);
  f32_to_bf16_pad<<<2048, 256, 0, stream>>>(W_out, Wout_bf, (long)DO * H, (long)DOP * H);
  f32_to_bf16_pad<<<4096, 256, 0, stream>>>(x, x_bf, (long)B * DI, (long)B * DI);
  transpose_pad_b<<<dim3(DI / 32, H / 32), 256, 0, stream>>>(W_in, WT_in_bf, H, DI, H);
  transpose_pad_b<<<dim3(H / 32, H / 32), 256, 0, stream>>>(W_rec, WT_rec_bf, H, H, H);
  transpose_pad_b<<<dim3(H / 32, DOP / 32), 256, 0, stream>>>(W_out, WT_out_bf, DOP, H, DO);

  // 2. Power iteration (bf16 weights, fp32 accum; unnormalized, scale-free)
  init_p<<<20, 256, 0, stream>>>(pvec);
  MatDescB B1a = {WT_in_bf, p_in, t_in, 1024, 2048, 2048};
  MatDescB B1b = {WT_rec_bf, p_rec, t_rec, 2048, 2048, 2048};
  MatDescB B1c = {WT_out_bf, p_out, t_out, 2048, 1024, 1024};
  MatDescB B2a = {Win_bf, t_in, p_in, 2048, 1024, 1024};
  MatDescB B2b = {Wrec_bf, t_rec, p_rec, 2048, 2048, 2048};
  MatDescB B2c = {Wout_bf, t_out, p_out, 1024, 2048, 2048};
  for (int it = 0; it < NSTEPS; ++it) {
    matvec3b<<<1280, 256, 0, stream>>>(B1a, B1b, B1c, 256, 512);
    matvec3b<<<1280, 256, 0, stream>>>(B2a, B2b, B2c, 512, 512);
  }
  matvec3b<<<1280, 256, 0, stream>>>(B1a, B1b, B1c, 256, 512);  // t = W^T u

  // 3. sigma via exact fp32 W: c_i = p_i * (row_i(W) . t); then 1/sigma
  MatDesc sa = {W_in, t_in, cbuf, p_in, 2048, 1024, 1024, 2048};
  MatDesc sb = {W_rec, t_rec, cbuf + 2048, p_rec, 2048, 2048, 2048, 2048};
  MatDesc sc = {W_out, t_out, cbuf + 4096, p_out, 1024, 2048, 2048, 1000};
  matvec3<<<1280, 256, 0, stream>>>(sa, sb, sc, 512, 512);
  finalize_sigma<<<1, 256, 0, stream>>>(pvec, tvec, cbuf, scal);

  // 4. xpb = bf16(x @ Win^T * is0 + b_in + b_rec)
  gemm8p<0><<<16 * 16, 512, 0, stream>>>(
      x_bf, Win_bf, H, DI, 16, 16, b_in, b_rec, nullptr, scal + 0, nullptr,
      xpb, H);

  // 5. h1 = tanh(xpb); then 29 recurrent GEMM steps ping-pong
  h1b<<<4096, 256, 0, stream>>>(xpb, h_a, (long)B * H);
  const unsigned short* hin = h_a;
  unsigned short* hout = h_b;
  for (int s = 2; s <= NSTEPS; ++s) {
    gemm8p<1><<<16 * 16, 512, 0, stream>>>(
        hin, Wrec_bf, H, H, 16, 16, nullptr, nullptr, xpb, scal + 1, nullptr,
        hout, H);
    const unsigned short* tmp = hin;
    hin = hout;
    hout = (unsigned short*)tmp;
  }

  // 6. out = h @ Wout^T * is2 + b_out  (N padded to 1024, stores guarded)
  gemm8p<2><<<16 * 8, 512, 0, stream>>>(
      hin, Wout_bf, DOP, H, 16, 8, b_out, nullptr, nullptr, scal + 2,
      (float*)d_out, nullptr, DO);
}